// Round 9
// baseline (227.340 us; speedup 1.0000x reference)
//
#include <hip/hip_runtime.h>

#define NS 65536      // B*H*W samples
#define D 64          // embed dim
#define K 1024        // codebook size
#define NEL 4194304   // NS*D
#define XS 40         // padded row stride of transposed x in LDS (32+8):
                      // keeps 16B alignment for b128 reads, 2-way-free writes

// ---------------------------------------------------------------------------
// Prep: transpose codebook [D,K] -> [K,D], compute ||m_k||^2, zero loss acc.
// 16 blocks; coalesced across k; norm reduced across d-quarters via LDS.
// ---------------------------------------------------------------------------
__global__ __launch_bounds__(256) void vq_prep(
    const float* __restrict__ cm,   // [D,K]
    float* __restrict__ ct,         // [K,D]
    float* __restrict__ cnorm,      // [K]
    double* __restrict__ acc)
{
    const int tx = threadIdx.x;
    const int kl = tx & 63;               // k within block
    const int dq = tx >> 6;               // d-quarter 0..3
    const int k  = blockIdx.x * 64 + kl;
    if (blockIdx.x == 0 && tx == 0) *acc = 0.0;

    float v[16];
    float p = 0.f;
#pragma unroll
    for (int j = 0; j < 16; ++j) {
        float t = cm[(dq * 16 + j) * K + k];   // coalesced across k
        v[j] = t;
        p = fmaf(t, t, p);
    }
    float4* dst = (float4*)(ct + (size_t)k * D + dq * 16);
#pragma unroll
    for (int j = 0; j < 4; ++j)
        dst[j] = make_float4(v[4*j], v[4*j+1], v[4*j+2], v[4*j+3]);

    __shared__ float pn[4][64];
    pn[dq][kl] = p;
    __syncthreads();
    if (tx < 64)
        cnorm[blockIdx.x * 64 + tx] = (pn[0][tx] + pn[1][tx]) + (pn[2][tx] + pn[3][tx]);
}

// ---------------------------------------------------------------------------
// Main: register-tiled VALU GEMM. 2048 blocks x 256 threads.
// R8 vs R7: SAMPLE-split (32 samples/block, full K=1024 in-block) to double
// the offered blocks/CU (grid was the occupancy limiter: 1024 blocks = 4/CU
// offered, only 8 waves/CU resident, VALUBusy 65%). Thread = 8 samples x 8
// codes per tile, 2 tiles of 512 codes. x transposed in LDS with stride 40
// (pad 8): 16B-aligned b128 broadcast reads, 2-way (free) staging writes.
// ---------------------------------------------------------------------------
__global__ __launch_bounds__(256, 3) void vq_main(
    const float* __restrict__ xin,    // [NS,D]
    const float* __restrict__ ct,     // [K,D]
    const float* __restrict__ cnorm,  // [K]
    float* __restrict__ outq,         // [NS,D]
    float* __restrict__ outidx,       // [NS] (indices as float)
    double* __restrict__ acc_g)
{
    // Region A (16 KB): x_lds[64*XS=2560 floats] during GEMM; after a
    // barrier reused as sbv[64*32] + siv[64*32]; then first 1 KB as red[256].
    __shared__ float smemA[4096];
    __shared__ float cn_lds[1024];    // 4 KB
    __shared__ int   widx[32];

    float* x_lds = smemA;                    // [d][s] stride XS
    float* sbv   = smemA;                    // [64][32]
    int*   siv   = (int*)(smemA + 2048);     // [64][32]
    float* red   = smemA;                    // [256]

    const int tx = threadIdx.x;
    const int sg = tx & 3;      // sample octet 0..3 (8 samples each)
    const int kg = tx >> 2;     // code lane 0..63
    const int S0 = blockIdx.x * 32;

    // ---- stage x transposed into LDS [d][s] (stride XS); stage cnorm ----
    {
        const int s  = tx & 31;          // sample 0..31
        const int dg = tx >> 5;          // dim-group 0..7 (dims dg*8..+7)
        const float* gp = xin + (size_t)(S0 + s) * D + dg * 8;
        float4 a = ((const float4*)gp)[0];
        float4 b = ((const float4*)gp)[1];
        x_lds[(dg*8 + 0) * XS + s] = a.x;
        x_lds[(dg*8 + 1) * XS + s] = a.y;
        x_lds[(dg*8 + 2) * XS + s] = a.z;
        x_lds[(dg*8 + 3) * XS + s] = a.w;
        x_lds[(dg*8 + 4) * XS + s] = b.x;
        x_lds[(dg*8 + 5) * XS + s] = b.y;
        x_lds[(dg*8 + 6) * XS + s] = b.z;
        x_lds[(dg*8 + 7) * XS + s] = b.w;
#pragma unroll
        for (int q = 0; q < 4; ++q) cn_lds[q*256 + tx] = cnorm[q*256 + tx];
    }
    __syncthreads();

    float best[8];
    int   bidx[8];
#pragma unroll
    for (int i = 0; i < 8; ++i) { best[i] = 3.4e38f; bidx[i] = 0; }

    // ---- 2 tiles of 512 codes; thread's codes k = t*512 + j*64 + kg ----
    for (int t = 0; t < 2; ++t) {
        float acc[8][8];
#pragma unroll
        for (int i = 0; i < 8; ++i)
#pragma unroll
            for (int j = 0; j < 8; ++j) acc[i][j] = 0.f;

        const float* mbase = ct + (size_t)(t*512 + kg) * D;

        for (int dc = 0; dc < 16; ++dc) {       // 16 chunks of 4 dims
            // x: 4 dims x 8 samples per dc (8 b128 broadcast reads)
            float4 xs[8];
#pragma unroll
            for (int dd = 0; dd < 4; ++dd) {
                const float* xr = x_lds + (dc*4 + dd)*XS + sg*8;
                xs[2*dd]     = *(const float4*)(xr);
                xs[2*dd + 1] = *(const float4*)(xr + 4);
            }
#pragma unroll
            for (int h = 0; h < 2; ++h) {       // two j-halves of 4 codes
                float4 mf[4];
#pragma unroll
                for (int j = 0; j < 4; ++j)
                    mf[j] = *(const float4*)(mbase + (size_t)(h*4 + j)*64*D + dc*4);
#pragma unroll
                for (int dd = 0; dd < 4; ++dd) {
                    const float4 xa = xs[2*dd];
                    const float4 xb = xs[2*dd + 1];
#pragma unroll
                    for (int j = 0; j < 4; ++j) {
                        const float ms = (dd == 0) ? mf[j].x :
                                         (dd == 1) ? mf[j].y :
                                         (dd == 2) ? mf[j].z : mf[j].w;
                        const int jj = h*4 + j;
                        acc[0][jj] = fmaf(xa.x, ms, acc[0][jj]);
                        acc[1][jj] = fmaf(xa.y, ms, acc[1][jj]);
                        acc[2][jj] = fmaf(xa.z, ms, acc[2][jj]);
                        acc[3][jj] = fmaf(xa.w, ms, acc[3][jj]);
                        acc[4][jj] = fmaf(xb.x, ms, acc[4][jj]);
                        acc[5][jj] = fmaf(xb.y, ms, acc[5][jj]);
                        acc[6][jj] = fmaf(xb.z, ms, acc[6][jj]);
                        acc[7][jj] = fmaf(xb.w, ms, acc[7][jj]);
                    }
                }
            }
        }
        // distances + running argmin (t,j ascending => k ascending, strict <)
#pragma unroll
        for (int j = 0; j < 8; ++j) {
            const int k = t*512 + j*64 + kg;
            const float cnv = cn_lds[k];
#pragma unroll
            for (int i = 0; i < 8; ++i) {
                float dist = fmaf(-2.f, acc[i][j], cnv);
                if (dist < best[i]) { best[i] = dist; bidx[i] = k; }
            }
        }
    }

    // ---- combine across the 64 kg-threads per sample ----
    __syncthreads();   // x_lds dead before sbv/siv overwrite the region
#pragma unroll
    for (int i = 0; i < 8; ++i) {
        sbv[kg*32 + sg*8 + i] = best[i];
        siv[kg*32 + sg*8 + i] = bidx[i];
    }
    __syncthreads();
    if (tx < 32) {
        float b = sbv[tx];
        int   w = siv[tx];
#pragma unroll
        for (int p = 1; p < 64; ++p) {
            float bp = sbv[p*32 + tx];
            if (bp < b) { b = bp; w = siv[p*32 + tx]; }
        }
        widx[tx] = w;
    }
    __syncthreads();   // after this, sbv/siv dead -> red may reuse region

    // ---- gather + STE output + loss partial ----
    const int sl = tx >> 3;                 // local sample 0..31
    const int d0 = (tx & 7) * 8;            // dim offset
    const int gs = S0 + sl;
    const int w  = widx[sl];
    const float* mq = ct + ((size_t)w << 6) + d0;
    const float* xr = xin + (size_t)gs * D + d0;
    float*       oq = outq + (size_t)gs * D + d0;
    float psum = 0.f;
#pragma unroll
    for (int j = 0; j < 8; j += 4) {
        float4 q  = *(const float4*)(mq + j);
        float4 xv = *(const float4*)(xr + j);
        float4 o;
        float dx = q.x - xv.x, dy = q.y - xv.y, dz = q.z - xv.z, dw = q.w - xv.w;
        o.x = xv.x + dx; o.y = xv.y + dy; o.z = xv.z + dz; o.w = xv.w + dw;
        *(float4*)(oq + j) = o;
        psum = fmaf(dx, dx, psum);
        psum = fmaf(dy, dy, psum);
        psum = fmaf(dz, dz, psum);
        psum = fmaf(dw, dw, psum);
    }

    if (tx < 32)
        outidx[S0 + tx] = (float)widx[tx];

    red[tx] = psum;
    __syncthreads();
    for (int st = 128; st > 0; st >>= 1) {
        if (tx < st) red[tx] += red[tx + st];
        __syncthreads();
    }
    if (tx == 0) atomicAdd(acc_g, (double)red[0]);
}

// ---------------------------------------------------------------------------
// Finalize: loss = m + 0.25*m where m = mean((q-x)^2)
// ---------------------------------------------------------------------------
__global__ void vq_finalize(const double* __restrict__ acc,
                            float* __restrict__ loss_out)
{
    float m = (float)(*acc / (double)NEL);
    *loss_out = m + 0.25f * m;
}

extern "C" void kernel_launch(void* const* d_in, const int* in_sizes, int n_in,
                              void* d_out, int out_size, void* d_ws, size_t ws_size,
                              hipStream_t stream) {
    const float* xin = (const float*)d_in[0];   // [16,64,64,64] fp32
    const float* cm  = (const float*)d_in[1];   // [64,1024] fp32

    float* out     = (float*)d_out;
    float* outq    = out;                 // 4194304 floats
    float* outidx  = out + NEL;           // 65536 floats (indices)
    float* outloss = out + NEL + NS;      // 1 float

    float*  ct    = (float*)d_ws;         // 65536 floats = 256 KB
    float*  cnorm = ct + (size_t)K * D;   // 1024 floats
    double* acc   = (double*)(cnorm + K); // 8B-aligned

    vq_prep<<<16, 256, 0, stream>>>(cm, ct, cnorm, acc);
    vq_main<<<2048, 256, 0, stream>>>(xin, ct, cnorm, outq, outidx, acc);
    vq_finalize<<<1, 1, 0, stream>>>(acc, outloss);
}

// Round 10
// 199.571 us; speedup vs baseline: 1.1391x; 1.1391x over previous
//
#include <hip/hip_runtime.h>
#include <stdint.h>

#define NS 65536      // B*H*W samples
#define D 64          // embed dim
#define K 1024        // codebook size
#define NEL 4194304   // NS*D
#define MARGIN 0.05f  // approx-dist uncertainty margin (>> 2*eps ~ 1.4e-3)

typedef short bf16x8 __attribute__((ext_vector_type(8)));
typedef float f32x4 __attribute__((ext_vector_type(4)));

static __device__ __forceinline__ unsigned short bf16_rne(float x) {
    union { float f; uint32_t u; } v; v.f = x;
    uint32_t r = v.u + 0x7FFFu + ((v.u >> 16) & 1u);
    return (unsigned short)(r >> 16);
}
static __device__ __forceinline__ float bf16f(unsigned short h) {
    union { uint32_t u; float f; } v; v.u = ((uint32_t)h) << 16;
    return v.f;
}

// ---------------------------------------------------------------------------
// Prep: split codebook into bf16 hi/lo [K][D] row-major (MFMA-B-ready),
// compute ||m_k||^2 in fp32, zero the loss accumulator.
// ---------------------------------------------------------------------------
__global__ __launch_bounds__(256) void vq_prep(
    const float* __restrict__ cm,        // [D,K]
    unsigned short* __restrict__ mhi,    // [K,D] bf16 bits
    unsigned short* __restrict__ mlo,    // [K,D] bf16 bits
    float* __restrict__ cnorm,           // [K]
    double* __restrict__ acc)
{
    const int tx = threadIdx.x;
    const int kl = tx & 63, dq = tx >> 6;
    const int k = blockIdx.x * 64 + kl;
    if (blockIdx.x == 0 && tx == 0) *acc = 0.0;

    unsigned short h[16], lo[16];
    float p = 0.f;
#pragma unroll
    for (int j = 0; j < 16; ++j) {
        float v = cm[(dq*16 + j) * K + k];   // coalesced across k
        unsigned short hb = bf16_rne(v);
        h[j] = hb;
        lo[j] = bf16_rne(v - bf16f(hb));
        p = fmaf(v, v, p);
    }
    bf16x8 v0, v1, w0, w1;
#pragma unroll
    for (int j = 0; j < 8; ++j) {
        v0[j] = (short)h[j];  v1[j] = (short)h[8+j];
        w0[j] = (short)lo[j]; w1[j] = (short)lo[8+j];
    }
    *(bf16x8*)(mhi + (size_t)k*D + dq*16)     = v0;
    *(bf16x8*)(mhi + (size_t)k*D + dq*16 + 8) = v1;
    *(bf16x8*)(mlo + (size_t)k*D + dq*16)     = w0;
    *(bf16x8*)(mlo + (size_t)k*D + dq*16 + 8) = w1;

    __shared__ float pn[4][64];
    pn[dq][kl] = p;
    __syncthreads();
    if (tx < 64)
        cnorm[blockIdx.x*64 + tx] = (pn[0][tx]+pn[1][tx]) + (pn[2][tx]+pn[3][tx]);
}

// ---------------------------------------------------------------------------
// Main: MFMA bf16-split distance GEMM. 1024 blocks x 256 thr (4 waves).
// Wave w: 16 samples x all 1024 codes in 64 iters of 16 codes.
// dot = x_hi.m_hi + x_hi.m_lo + x_lo.m_hi  (3 chains, 6 MFMA/iter).
// x frags are K-loop invariant (16 VGPRs). Per-lane top-2 + LDS merge;
// margin cases rescored exactly in fp32 from original cm.
// A-frag: A[m=lane&15][k=quad*8+j]; C/D: col(code)=lane&15,
// row(sample)=quad*4+reg  [guide §3, m89/m120 verified].
// ---------------------------------------------------------------------------
__global__ __launch_bounds__(256, 4) void vq_main(
    const float* __restrict__ xin,           // [NS,D]
    const float* __restrict__ cm,            // [D,K] (exact rescore)
    const unsigned short* __restrict__ mhi,  // [K,D]
    const unsigned short* __restrict__ mlo,  // [K,D]
    const float* __restrict__ cnorm,         // [K]
    float* __restrict__ outq,                // [NS,D]
    float* __restrict__ outidx,              // [NS]
    double* __restrict__ acc_g)
{
    // phase1: xh[64][72] + xl[64][72] bf16 (18432 B)
    // phase2 (alias): mb1/mb2 f32[1024] + mi1/mi2 i32[1024] (16384 B)
    // phase3 (alias): red f32[256]
    __shared__ char smem[18432];
    __shared__ float cn_lds[1024];
    __shared__ int   widx[64];

    unsigned short* xh = (unsigned short*)smem;           // stride 72
    unsigned short* xl = (unsigned short*)(smem + 9216);
    float* mb1 = (float*)smem;
    float* mb2 = (float*)(smem + 4096);
    int*   mi1 = (int*)(smem + 8192);
    int*   mi2 = (int*)(smem + 12288);
    float* red = (float*)smem;

    const int tx = threadIdx.x;
    const int S0 = blockIdx.x * 64;

    // ---- stage x -> bf16 hi/lo in LDS ----
    {
        const int s = tx >> 2, d0 = (tx & 3) * 16;
        const float* gp = xin + (size_t)(S0 + s) * D + d0;
#pragma unroll
        for (int j = 0; j < 16; ++j) {
            float v = gp[j];
            unsigned short hb = bf16_rne(v);
            xh[s*72 + d0 + j] = hb;
            xl[s*72 + d0 + j] = bf16_rne(v - bf16f(hb));
        }
#pragma unroll
        for (int q = 0; q < 4; ++q) cn_lds[q*256 + tx] = cnorm[q*256 + tx];
    }
    __syncthreads();

    const int w = tx >> 6, l = tx & 63;
    const int quad = l >> 4, col = l & 15;

    // loop-invariant A fragments: sample row = w*16 + col, dims quad*8..+8
    const int srow = w*16 + col;
    bf16x8 ahi0 = *(const bf16x8*)(xh + srow*72 + quad*8);
    bf16x8 ahi1 = *(const bf16x8*)(xh + srow*72 + 32 + quad*8);
    bf16x8 alo0 = *(const bf16x8*)(xl + srow*72 + quad*8);
    bf16x8 alo1 = *(const bf16x8*)(xl + srow*72 + 32 + quad*8);

    float b1[4], b2[4]; int i1[4], i2[4];
#pragma unroll
    for (int r = 0; r < 4; ++r) { b1[r]=3.4e38f; b2[r]=3.4e38f; i1[r]=0; i2[r]=0; }

    // B frags: lane supplies code = kb*16 + col, dims quad*8+j
    const unsigned short* bh = mhi + (size_t)col*D + quad*8;
    const unsigned short* bl = mlo + (size_t)col*D + quad*8;

    for (int kb = 0; kb < 64; ++kb) {
        bf16x8 bh0 = *(const bf16x8*)(bh);
        bf16x8 bh1 = *(const bf16x8*)(bh + 32);
        bf16x8 bl0 = *(const bf16x8*)(bl);
        bf16x8 bl1 = *(const bf16x8*)(bl + 32);
        f32x4 z = {0.f, 0.f, 0.f, 0.f};
        f32x4 hh = __builtin_amdgcn_mfma_f32_16x16x32_bf16(ahi0, bh0, z, 0,0,0);
        hh       = __builtin_amdgcn_mfma_f32_16x16x32_bf16(ahi1, bh1, hh, 0,0,0);
        f32x4 hl = __builtin_amdgcn_mfma_f32_16x16x32_bf16(ahi0, bl0, z, 0,0,0);
        hl       = __builtin_amdgcn_mfma_f32_16x16x32_bf16(ahi1, bl1, hl, 0,0,0);
        f32x4 lh = __builtin_amdgcn_mfma_f32_16x16x32_bf16(alo0, bh0, z, 0,0,0);
        lh       = __builtin_amdgcn_mfma_f32_16x16x32_bf16(alo1, bh1, lh, 0,0,0);
        const int kcode = kb*16 + col;
        const float cn = cn_lds[kcode];
#pragma unroll
        for (int r = 0; r < 4; ++r) {
            float dot = (hh[r] + hl[r]) + lh[r];
            float d = fmaf(-2.f, dot, cn);
            bool c1 = d < b1[r];
            bool c2 = d < b2[r];
            b2[r] = c1 ? b1[r] : (c2 ? d : b2[r]);
            i2[r] = c1 ? i1[r] : (c2 ? kcode : i2[r]);
            b1[r] = c1 ? d : b1[r];
            i1[r] = c1 ? kcode : i1[r];
        }
        bh += 16*D;
        bl += 16*D;
    }

    // ---- merge per-lane top-2 across the 16 lanes per (wave,quad,reg) ----
    __syncthreads();   // xh/xl dead (frags in regs) before alias overwrite
#pragma unroll
    for (int r = 0; r < 4; ++r) {
        mb1[tx*4 + r] = b1[r];
        mb2[tx*4 + r] = b2[r];
        mi1[tx*4 + r] = i1[r];
        mi2[tx*4 + r] = i2[r];
    }
    __syncthreads();

    if (tx < 64) {   // thread tx owns local sample tx
        const int mw = tx >> 4, mq = (tx >> 2) & 3, mr = tx & 3;
        float B1 = 3.4e38f, B2 = 3.4e38f; int I1 = 0, I2 = 0;
#pragma unroll
        for (int c = 0; c < 16; ++c) {
            const int e = (mw*64 + mq*16 + c)*4 + mr;
            float v1 = mb1[e]; int j1 = mi1[e];
            float v2 = mb2[e]; int j2 = mi2[e];
            if (v1 < B1)      { B2 = B1; I2 = I1; B1 = v1; I1 = j1; }
            else if (v1 < B2) { B2 = v1; I2 = j1; }
            if (v2 < B1)      { B2 = B1; I2 = I1; B1 = v2; I1 = j2; }
            else if (v2 < B2) { B2 = v2; I2 = j2; }
        }
        int winner = I1;
        if (B2 - B1 < MARGIN) {
            // exact fp32 rescore of both candidates from original cm
            const float* xp = xin + (size_t)(S0 + tx) * D;
            float a0=0,a1=0,a2=0,a3=0, e0=0,e1=0,e2=0,e3=0;
            for (int dd = 0; dd < D; dd += 4) {
                float x0 = xp[dd], x1 = xp[dd+1], x2 = xp[dd+2], x3 = xp[dd+3];
                a0 = fmaf(x0, cm[(dd+0)*K + I1], a0);
                a1 = fmaf(x1, cm[(dd+1)*K + I1], a1);
                a2 = fmaf(x2, cm[(dd+2)*K + I1], a2);
                a3 = fmaf(x3, cm[(dd+3)*K + I1], a3);
                e0 = fmaf(x0, cm[(dd+0)*K + I2], e0);
                e1 = fmaf(x1, cm[(dd+1)*K + I2], e1);
                e2 = fmaf(x2, cm[(dd+2)*K + I2], e2);
                e3 = fmaf(x3, cm[(dd+3)*K + I2], e3);
            }
            float d1 = fmaf(-2.f, (a0+a1)+(a2+a3), cn_lds[I1]);
            float d2 = fmaf(-2.f, (e0+e1)+(e2+e3), cn_lds[I2]);
            if (d2 < d1 || (d2 == d1 && I2 < I1)) winner = I2;
        }
        widx[tx] = winner;
    }
    __syncthreads();

    // ---- gather (hi+lo reconstruct, coalesced) + STE + loss partial ----
    const int sl = tx >> 2, d0 = (tx & 3) * 16;
    const int gs = S0 + sl;
    const int wi = widx[sl];
    const unsigned short* mh = mhi + (size_t)wi*D + d0;
    const unsigned short* ml = mlo + (size_t)wi*D + d0;
    bf16x8 h0 = *(const bf16x8*)(mh);
    bf16x8 h1 = *(const bf16x8*)(mh + 8);
    bf16x8 l0 = *(const bf16x8*)(ml);
    bf16x8 l1 = *(const bf16x8*)(ml + 8);
    const float* xr = xin + (size_t)gs*D + d0;
    float* oq = outq + (size_t)gs*D + d0;
    float psum = 0.f;
#pragma unroll
    for (int g = 0; g < 4; ++g) {
        float4 xv = *(const float4*)(xr + 4*g);
        float q0 = bf16f((unsigned short)(g < 2 ? h0[4*g+0] : h1[4*g-8+0])) +
                   bf16f((unsigned short)(g < 2 ? l0[4*g+0] : l1[4*g-8+0]));
        float q1 = bf16f((unsigned short)(g < 2 ? h0[4*g+1] : h1[4*g-8+1])) +
                   bf16f((unsigned short)(g < 2 ? l0[4*g+1] : l1[4*g-8+1]));
        float q2 = bf16f((unsigned short)(g < 2 ? h0[4*g+2] : h1[4*g-8+2])) +
                   bf16f((unsigned short)(g < 2 ? l0[4*g+2] : l1[4*g-8+2]));
        float q3 = bf16f((unsigned short)(g < 2 ? h0[4*g+3] : h1[4*g-8+3])) +
                   bf16f((unsigned short)(g < 2 ? l0[4*g+3] : l1[4*g-8+3]));
        float dx = q0 - xv.x, dy = q1 - xv.y, dz = q2 - xv.z, dw = q3 - xv.w;
        float4 o;
        o.x = xv.x + dx; o.y = xv.y + dy; o.z = xv.z + dz; o.w = xv.w + dw;
        *(float4*)(oq + 4*g) = o;
        psum = fmaf(dx, dx, psum);
        psum = fmaf(dy, dy, psum);
        psum = fmaf(dz, dz, psum);
        psum = fmaf(dw, dw, psum);
    }

    if (tx < 64)
        outidx[S0 + tx] = (float)widx[tx];

    red[tx] = psum;
    __syncthreads();
    for (int st = 128; st > 0; st >>= 1) {
        if (tx < st) red[tx] += red[tx + st];
        __syncthreads();
    }
    if (tx == 0) atomicAdd(acc_g, (double)red[0]);
}

// ---------------------------------------------------------------------------
// Finalize: loss = m + 0.25*m where m = mean((q-x)^2)
// ---------------------------------------------------------------------------
__global__ void vq_finalize(const double* __restrict__ acc,
                            float* __restrict__ loss_out)
{
    float m = (float)(*acc / (double)NEL);
    *loss_out = m + 0.25f * m;
}

extern "C" void kernel_launch(void* const* d_in, const int* in_sizes, int n_in,
                              void* d_out, int out_size, void* d_ws, size_t ws_size,
                              hipStream_t stream) {
    const float* xin = (const float*)d_in[0];   // [16,64,64,64] fp32
    const float* cm  = (const float*)d_in[1];   // [64,1024] fp32

    float* out     = (float*)d_out;
    float* outq    = out;                 // 4194304 floats
    float* outidx  = out + NEL;           // 65536 floats (indices)
    float* outloss = out + NEL + NS;      // 1 float

    // workspace: mhi 128 KB | mlo 128 KB | cnorm 4 KB | acc 8 B (= 266 KB,
    // same envelope as all previous passing rounds)
    unsigned short* mhi = (unsigned short*)d_ws;
    unsigned short* mlo = mhi + (size_t)K * D;
    float*  cnorm = (float*)((char*)d_ws + 262144);
    double* acc   = (double*)((char*)d_ws + 266240);

    vq_prep<<<16, 256, 0, stream>>>(cm, mhi, mlo, cnorm, acc);
    vq_main<<<1024, 256, 0, stream>>>(xin, cm, mhi, mlo, cnorm, outq, outidx, acc);
    vq_finalize<<<1, 1, 0, stream>>>(acc, outloss);
}